// Round 7
// baseline (225.760 us; speedup 1.0000x reference)
//
#include <hip/hip_runtime.h>

#define NB    131072   // batch rows
#define TPB   512      // 8 waves/block; block owns 64 contiguous rows; wave wv owns k[wv*32, wv*32+32)
#define FANIN 260

__device__ __forceinline__ float sigm_(float x) { return 1.0f / (1.0f + __expf(-x)); }
__device__ __forceinline__ float tanh_(float x) { return 1.0f - 2.0f / (__expf(2.0f * x) + 1.0f); }

// Async global->LDS, 16 B/lane. Dest = wave-uniform base + lane*16 (linear, HW
// rule m104); swizzle therefore lives on the per-lane GLOBAL address (m173).
__device__ __forceinline__ void gld_lds16(const float4* gsrc, float4* ldst) {
    __builtin_amdgcn_global_load_lds(
        (const __attribute__((address_space(1))) void*)gsrc,
        (__attribute__((address_space(3))) void*)ldst, 16, 0, 0);
}

// Repack the four [4,260] weight matrices into k-major Wp[k][16] (gw = g*4+w)
// and fuse bias+theta into bth[16]. ws re-poison is UNCONDITIONAL (measured r1),
// so using the workspace costs nothing.
__global__ void qlstm_prep(const float* __restrict__ Wf, const float* __restrict__ bf,
                           const float* __restrict__ Wi, const float* __restrict__ bi,
                           const float* __restrict__ Wu, const float* __restrict__ bu,
                           const float* __restrict__ Wo, const float* __restrict__ bo,
                           const float* __restrict__ thf, const float* __restrict__ thi,
                           const float* __restrict__ thu, const float* __restrict__ tho,
                           float* __restrict__ Wp, float* __restrict__ bth) {
    int t = blockIdx.x * blockDim.x + threadIdx.x;
    if (t < FANIN * 16) {
        int k = t >> 4, gw = t & 15, g = gw >> 2, w = gw & 3;
        const float* Wg = (g == 0) ? Wf : (g == 1) ? Wi : (g == 2) ? Wu : Wo;
        Wp[t] = Wg[w * FANIN + k];
    }
    if (t < 16) {
        int g = t >> 2, w = t & 3;
        const float* bg = (g == 0) ? bf  : (g == 1) ? bi  : (g == 2) ? bu  : bo;
        const float* tg = (g == 0) ? thf : (g == 1) ? thi : (g == 2) ? thu : tho;
        bth[t] = bg[w] + tg[w];
    }
}

__global__ __launch_bounds__(TPB, 4) void qlstm_main(
        const float* __restrict__ x, const float* __restrict__ hx,
        const float* __restrict__ cx, const float* __restrict__ Wp,
        const float* __restrict__ bth, float* __restrict__ out) {
    // 64 rows x 64 float4 = 64 KB (exactly) -> 2 blocks/CU = 16 waves/CU.
    // Physical layout: xt[r*64 + p] holds x[row0+r][p ^ (r&7)] (float4 cols).
    // First 28 KB is reused as the partial-acc exchange buffer after the FMA
    // phase (barrier-separated alias).
    __shared__ float4 xt[64 * 64];

    const int tid  = threadIdx.x;
    const int lane = tid & 63;
    const int wv   = tid >> 6;
    const int wvu  = __builtin_amdgcn_readfirstlane(wv);   // SGPR wave id
    const int row0 = blockIdx.x * 64;
    const int row  = row0 + lane;

    const float4* x4 = (const float4*)x + (size_t)row0 * 64;  // block's 64-KB span

    float4 hv  = make_float4(0.f, 0.f, 0.f, 0.f);
    float4 cxv = make_float4(0.f, 0.f, 0.f, 0.f);
    if (wvu == 7) hv  = ((const float4*)hx)[row];   // tail owner
    if (wvu == 0) cxv = ((const float4*)cx)[row];   // epilogue owner

    // ---- Stage: pure LINEAR 64-KB sweep (the experiment's variable).
    // Instruction r = wv*8+i copies the 1-KB burst of row r: global source
    // column (lane ^ (r&7)) stays inside each 128-B line -> full coalescing;
    // LDS dest &xt[r*64] is wave-uniform + lane*16 (linear, as HW requires).
    // 8 instrs/wave x 64 waves-in-flight worth of bursts walk the span in order.
#pragma unroll
    for (int i = 0; i < 8; ++i) {
        const int r = wvu * 8 + i;
        gld_lds16(x4 + (size_t)r * 64 + (lane ^ (r & 7)), &xt[r * 64]);
    }
    asm volatile("s_waitcnt vmcnt(0)" ::: "memory");
    __syncthreads();

    float acc[16];
#pragma unroll
    for (int j = 0; j < 16; ++j) acc[j] = 0.0f;

    // ---- FMA phase: own row from LDS (8 x ds_read_b128, conflict-free:
    // bank-quad = (c4 ^ (lane&7)) & 7 covers all 8 per 8-lane group);
    // weights via wave-uniform s_load (r5 measured LDS-broadcast strictly worse).
    const float* wbase = Wp + wvu * 32 * 16;
#pragma unroll
    for (int j = 0; j < 8; ++j) {
        float4 xv = xt[lane * 64 + ((wvu * 8 + j) ^ (lane & 7))];
#pragma unroll
        for (int m = 0; m < 4; ++m) {
            float xe = (m == 0) ? xv.x : (m == 1) ? xv.y : (m == 2) ? xv.z : xv.w;
            const float* wp = wbase + (j * 4 + m) * 16;
#pragma unroll
            for (int jj = 0; jj < 16; ++jj) acc[jj] = fmaf(xe, wp[jj], acc[jj]);
        }
    }

    if (wvu == 7) {
        // Tail: k = 256..259 from hx[row][0..3].
        const float* wp = Wp + 256 * 16;
#pragma unroll
        for (int j = 0; j < 16; ++j) acc[j] = fmaf(hv.x, wp[j],      acc[j]);
#pragma unroll
        for (int j = 0; j < 16; ++j) acc[j] = fmaf(hv.y, wp[16 + j], acc[j]);
#pragma unroll
        for (int j = 0; j < 16; ++j) acc[j] = fmaf(hv.z, wp[32 + j], acc[j]);
#pragma unroll
        for (int j = 0; j < 16; ++j) acc[j] = fmaf(hv.w, wp[48 + j], acc[j]);
    }

    __syncthreads();              // all xt reads done -> alias as exchange buffer
    float* accx = (float*)xt;     // [j][srcwave 0..6][lane], 28 KB, b32 conflict-free
    if (wvu != 0) {
#pragma unroll
        for (int j = 0; j < 16; ++j)
            accx[(j * 7 + (wvu - 1)) * 64 + lane] = acc[j];
    }
    __syncthreads();

    if (wvu == 0) {
#pragma unroll
        for (int j = 0; j < 16; ++j) {
            float s = acc[j];
#pragma unroll
            for (int p = 0; p < 7; ++p) s += accx[(j * 7 + p) * 64 + lane];
            acc[j] = s;
        }

        // ---- Quantum gate closed form ----
        // c_w = cos(angle_w + b_w + th_w); E0=c1*c2*c3, E1=c0*c1, E2=c0*c1*c2, E3=c0*c1*c2*c3
        float co[16];
#pragma unroll
        for (int j = 0; j < 16; ++j) co[j] = __cosf(acc[j] + bth[j]);

        float G[16];
#pragma unroll
        for (int g = 0; g < 4; ++g) {
            float c0 = co[g * 4 + 0], c1 = co[g * 4 + 1];
            float c2 = co[g * 4 + 2], c3 = co[g * 4 + 3];
            float e1 = c0 * c1;
            float e2 = e1 * c2;
            float e3 = e2 * c3;
            float e0 = c1 * c2 * c3;
            G[g * 4 + 0] = e0; G[g * 4 + 1] = e1; G[g * 4 + 2] = e2; G[g * 4 + 3] = e3;
        }

        float cxa[4] = {cxv.x, cxv.y, cxv.z, cxv.w};
        float hn[4], cn[4];
#pragma unroll
        for (int w = 0; w < 4; ++w) {
            float fg = sigm_(G[0 * 4 + w]);
            float ig = sigm_(G[1 * 4 + w]);
            float ug = tanh_(G[2 * 4 + w]);
            float og = sigm_(G[3 * 4 + w]);
            float c_ = fg * cxa[w] + ig * ug;
            cn[w] = c_;
            hn[w] = og * tanh_(c_);
        }

        ((float4*)out)[row]      = make_float4(hn[0], hn[1], hn[2], hn[3]);  // h_new
        ((float4*)out)[NB + row] = make_float4(cn[0], cn[1], cn[2], cn[3]);  // c_new
    }
}

extern "C" void kernel_launch(void* const* d_in, const int* in_sizes, int n_in,
                              void* d_out, int out_size, void* d_ws, size_t ws_size,
                              hipStream_t stream) {
    const float* x   = (const float*)d_in[0];
    const float* hx  = (const float*)d_in[1];
    const float* cx  = (const float*)d_in[2];
    const float* Wf  = (const float*)d_in[3];
    const float* bf  = (const float*)d_in[4];
    const float* Wi  = (const float*)d_in[5];
    const float* bi  = (const float*)d_in[6];
    const float* Wu  = (const float*)d_in[7];
    const float* bu  = (const float*)d_in[8];
    const float* Wo  = (const float*)d_in[9];
    const float* bo  = (const float*)d_in[10];
    const float* thf = (const float*)d_in[11];
    const float* thi = (const float*)d_in[12];
    const float* thu = (const float*)d_in[13];
    const float* tho = (const float*)d_in[14];

    float* Wp  = (float*)d_ws;            // 260*16 floats
    float* bth = Wp + FANIN * 16;         // 16 floats

    qlstm_prep<<<(FANIN * 16 + 255) / 256, 256, 0, stream>>>(
        Wf, bf, Wi, bi, Wu, bu, Wo, bo, thf, thi, thu, tho, Wp, bth);

    qlstm_main<<<NB / 64, TPB, 0, stream>>>(
        x, hx, cx, Wp, bth, (float*)d_out);
}